// Round 6
// baseline (744.264 us; speedup 1.0000x reference)
//
#include <hip/hip_runtime.h>

// H=W=1024, T=16, 20 iterations. Intermediates in two zero-bordered padded
// buffers: PH x PITCH floats, pixel (h,w) at [(h+1)*PITCH + (w+1)]. Zero
// borders => all 4 bilinear corners of any in-range sample are loadable
// unconditionally (zeros padding is exact).
//
// R6 structure (attack TCP line-lookup bound):
//  - per (16x16 tile, transform): stage the source bbox (<=64x64 incl margin)
//    into LDS with row-contiguous COALESCED loads, then bilinear-sample from
//    LDS. Cuts L1 line lookups ~4-5x vs per-pixel scattered gathers.
//  - transforms with bbox > 64x64 (rare for N(0,1) theta) use the old
//    global-gather body.
//  - classification + list compaction inline (wave 0), no mask kernel.
constexpr int W = 1024;
constexpr int H = 1024;
constexpr int T = 16;
constexpr int ITERS = 20;
constexpr int PITCH = 1040;           // floats per padded row
constexpr int PH = H + 2;             // 1026 rows
constexpr int PAD_ELEMS = PH * PITCH;
constexpr int TILES_X = W / 16;       // 64
constexpr int TILES_Y = H / 16;       // 64
constexpr int LPITCH = 65;            // LDS stage pitch (odd -> bank-friendly)

typedef float f2 __attribute__((ext_vector_type(2), aligned(4)));

// coef per transform t: {p, Ax, Bx, Cxp, Ay, By, Cyp, 0}; Cxp/Cyp include the
// +1 pad shift, so ixp = Ax*w + Bx*h + Cxp is the PADDED x coordinate.
__global__ void setup_coef(const float* __restrict__ theta,
                           const float* __restrict__ probs,
                           float* __restrict__ coef) {
    int t = threadIdx.x;
    if (t >= T) return;
    float sum = 0.f;
    for (int i = 0; i < T; ++i) sum += probs[i];
    float p = probs[t] / sum;
    const float* th = theta + 6 * t;
    float a = th[0], b = th[1], c = th[2];
    float d = th[3], e = th[4], f = th[5];
    float Cx = a * ((1.0f - (float)W) * 0.5f)
             + b * ((1.0f - (float)H) * 0.5f)
             + (c + 1.0f) * ((float)W * 0.5f) - 0.5f;
    float Cy = d * ((1.0f - (float)W) * 0.5f)
             + e * ((1.0f - (float)H) * 0.5f)
             + (f + 1.0f) * ((float)H * 0.5f) - 0.5f;
    float* o = coef + 8 * t;
    o[0] = p;  o[1] = a;  o[2] = b;  o[3] = Cx + 1.0f;
    o[4] = d;  o[5] = e;  o[6] = Cy + 1.0f; o[7] = 0.f;
}

__global__ __launch_bounds__(256) void copy_in(const float* __restrict__ src,
                                               float* __restrict__ dst) {
    int i = blockIdx.x * 256 + threadIdx.x;   // i in [0, H*W)
    int h = i >> 10, w = i & 1023;
    dst[(h + 1) * PITCH + (w + 1)] = src[i];
}

__global__ __launch_bounds__(256) void ifs_iter(const float* __restrict__ in,
                                                float* __restrict__ out,
                                                const float* __restrict__ coef,
                                                const float* __restrict__ base,
                                                int dstPitch, int dstOff,
                                                int add_base) {
    __shared__ float sbuf[64 * LPITCH];   // 16.6 KB stage buffer
    __shared__ float mL[T][12];           // LDS-path transform meta
    __shared__ float mG[T][7];            // global-path transform meta
    __shared__ int   cnt[2];

    int lid  = threadIdx.x;
    int lane = lid & 63;
    int wv   = lid >> 6;

    if (lid == 0) { cnt[0] = 0; cnt[1] = 0; }
    // classification by wave 0, threads 0..15 (in-wave program order makes the
    // cnt[] init visible; atomic order is lane-ordered -> deterministic lists)
    if (lid < T) {
        const float* c = coef + lid * 8;
        float p = c[0], Ax = c[1], Bx = c[2], Cx = c[3];
        float Ay = c[4], By = c[5], Cy = c[6];
        float w0 = (float)(blockIdx.x * 16), w1 = w0 + 15.f;
        float h0 = (float)(blockIdx.y * 16), h1 = h0 + 15.f;
        float ixmin = Cx + (Ax >= 0.f ? Ax * w0 : Ax * w1) + (Bx >= 0.f ? Bx * h0 : Bx * h1);
        float ixmax = Cx + (Ax >= 0.f ? Ax * w1 : Ax * w0) + (Bx >= 0.f ? Bx * h1 : Bx * h0);
        float iymin = Cy + (Ay >= 0.f ? Ay * w0 : Ay * w1) + (By >= 0.f ? By * h0 : By * h1);
        float iymax = Cy + (Ay >= 0.f ? Ay * w1 : Ay * w0) + (By >= 0.f ? By * h1 : By * h0);
        // sample active iff ixp in [0,1025) and iyp in [0,1025) (conservative)
        bool hit = (ixmax >= 0.f) & (ixmin <= 1025.f) & (iymax >= 0.f) & (iymin <= 1025.f);
        if (hit) {
            // clamped bbox with 1-px rounding margin; all integers (exact fp)
            float xlo = fmaxf(floorf(ixmin) - 1.f, 0.f);
            float xhi = fminf(floorf(ixmax) + 2.f, 1025.f);
            float ylo = fmaxf(floorf(iymin) - 1.f, 0.f);
            float yhi = fminf(floorf(iymax) + 2.f, 1025.f);
            int bw = (int)(xhi - xlo) + 1;
            int bh = (int)(yhi - ylo) + 1;
            if (bw <= 64 && bh <= 64) {
                int s = atomicAdd(&cnt[0], 1);
                mL[s][0] = p;   mL[s][1] = Ax;  mL[s][2] = Bx;  mL[s][3] = Cx;
                mL[s][4] = Ay;  mL[s][5] = By;  mL[s][6] = Cy;
                mL[s][7] = xlo; mL[s][8] = ylo;
                mL[s][9]  = __int_as_float((int)fmaf(ylo, (float)PITCH, xlo));
                mL[s][10] = __int_as_float(bw);
                mL[s][11] = __int_as_float(bh);
            } else {
                int s = atomicAdd(&cnt[1], 1);
                mG[s][0] = p;  mG[s][1] = Ax; mG[s][2] = Bx; mG[s][3] = Cx;
                mG[s][4] = Ay; mG[s][5] = By; mG[s][6] = Cy;
            }
        }
    }
    __syncthreads();
    int nL = cnt[0], nG = cnt[1];

    // 8x8-per-wave mapping; 4 waves tile a 16x16 pixel block.
    int w = blockIdx.x * 16 + ((wv & 1) << 3) + (lane & 7);
    int h = blockIdx.y * 16 + ((wv >> 1) << 3) + (lane >> 3);
    float wf = (float)w, hf = (float)h;

    float acc = 0.f;

    // ---- LDS-staged transforms ----
    for (int i = 0; i < nL; ++i) {
        float p   = mL[i][0];
        float Ax  = mL[i][1], Bx = mL[i][2], Cx = mL[i][3];
        float Ay  = mL[i][4], By = mL[i][5], Cy = mL[i][6];
        float xlo = mL[i][7], ylo = mL[i][8];
        int gbase = __float_as_int(mL[i][9]);
        int bw    = __float_as_int(mL[i][10]);
        int bh    = __float_as_int(mL[i][11]);

        // stage bbox rows (coalesced); pack 4/2/1 rows per wave-pass by width
        int colbits = bw <= 16 ? 4 : (bw <= 32 ? 5 : 6);
        int rpp = 64 >> colbits;               // rows per wave-pass
        int c  = lane & ((1 << colbits) - 1);
        int rs = lane >> colbits;
        for (int rb = wv * rpp; rb < bh; rb += 4 * rpp) {
            int r = rb + rs;
            if (r < bh) sbuf[r * LPITCH + c] = in[gbase + r * PITCH + c];
        }
        __syncthreads();

        float x  = fmaf(Ax, wf, fmaf(Bx, hf, Cx));
        float y  = fmaf(Ay, wf, fmaf(By, hf, Cy));
        float xf = floorf(x), yf = floorf(y);
        bool act = (xf >= 0.f) & (xf <= (float)W) & (yf >= 0.f) & (yf <= (float)H);
        float lx = xf - xlo, ly = yf - ylo;               // small ints, exact
        int lidx = act ? (int)fmaf(ly, (float)LPITCH, lx) : 0;
        float pe = act ? p : 0.f;
        float v00 = sbuf[lidx],          v01 = sbuf[lidx + 1];
        float v10 = sbuf[lidx + LPITCH], v11 = sbuf[lidx + LPITCH + 1];
        float fx = x - xf, fy = y - yf;
        float top = fmaf(fx, v01 - v00, v00);
        float bot = fmaf(fx, v11 - v10, v10);
        acc = fmaf(pe, fmaf(fy, bot - top, top), acc);
        __syncthreads();   // protect sbuf before next transform's staging
    }

    // ---- rare wide transforms: direct global gather ----
    for (int i = 0; i < nG; ++i) {
        float p  = mG[i][0];
        float Ax = mG[i][1], Bx = mG[i][2], Cx = mG[i][3];
        float Ay = mG[i][4], By = mG[i][5], Cy = mG[i][6];
        float x  = fmaf(Ax, wf, fmaf(Bx, hf, Cx));
        float y  = fmaf(Ay, wf, fmaf(By, hf, Cy));
        float xf = floorf(x), yf = floorf(y);
        bool act = (xf >= 0.f) & (xf <= (float)W) & (yf >= 0.f) & (yf <= (float)H);
        int idx  = act ? (int)fmaf(yf, (float)PITCH, xf) : 0;   // exact (<2^24)
        float pe = act ? p : 0.f;
        f2 r0 = *(const f2*)(in + idx);
        f2 r1 = *(const f2*)(in + idx + PITCH);
        float fx = x - xf, fy = y - yf;
        float top = fmaf(fx, r0.y - r0.x, r0.x);
        float bot = fmaf(fx, r1.y - r1.x, r1.x);
        acc = fmaf(pe, fmaf(fy, bot - top, top), acc);
    }

    if (add_base) acc += base[0];
    out[h * dstPitch + w + dstOff] = acc;
}

extern "C" void kernel_launch(void* const* d_in, const int* in_sizes, int n_in,
                              void* d_out, int out_size, void* d_ws, size_t ws_size,
                              hipStream_t stream) {
    const float* canvas0 = (const float*)d_in[0];
    const float* theta   = (const float*)d_in[1];
    const float* probs   = (const float*)d_in[2];
    const float* base    = (const float*)d_in[3];
    float* out = (float*)d_out;

    float* bufA = (float*)d_ws;
    float* bufB = bufA + PAD_ELEMS;
    float* coef = bufB + PAD_ELEMS;

    // zero both padded buffers (borders must be 0; also kills 0xAA poison)
    hipMemsetAsync(d_ws, 0, (size_t)2 * PAD_ELEMS * sizeof(float), stream);

    setup_coef<<<1, 64, 0, stream>>>(theta, probs, coef);
    copy_in<<<(H * W) / 256, 256, 0, stream>>>(canvas0, bufA);

    dim3 block(256);
    dim3 grid(TILES_X, TILES_Y);

    const float* cur = bufA;
    for (int i = 0; i < ITERS; ++i) {
        bool last = (i == ITERS - 1);
        float* dst = last ? out : ((i & 1) ? bufA : bufB);
        int dstPitch = last ? W : PITCH;
        int dstOff   = last ? 0 : (PITCH + 1);
        ifs_iter<<<grid, block, 0, stream>>>(cur, dst, coef, base,
                                             dstPitch, dstOff, last ? 1 : 0);
        cur = dst;
    }
}